// Round 12
// baseline (17080.792 us; speedup 1.0000x reference)
//
#include <hip/hip_runtime.h>
#include <cstdint>

typedef unsigned u32t;
typedef float f32x4 __attribute__((ext_vector_type(4)));
typedef short s16x4 __attribute__((ext_vector_type(4)));

#define Qn   515
#define Bn   256
#define Tn   512
#define OQ   516
#define EPSc 1e-16f
#define NTT  33         // n-tiles (528 state cols)
#define KTT  34         // k-tiles (544 state rows)
#define KR   8          // LDS-resident k-tiles
#define ND   4          // stream prefetch depth (k-tiles)
#define NSTP 7          // ceil((KTT-KR)/ND)
#define ROWS 16         // batch rows per block
#define NBLK 16         // blocks (16*16 = 256 = B)
#define VSTR 552        // vstage row stride in ushorts (1104 B)

// workspace layout (bytes)
#define WS_AMATH 0                           // 544*260*4 = 565,760 (bf16-pair packed A)
#define WS_INIT  565760                      // 520*4, pad to 568,320
#define WS_FRAGG 568320                      // 34*33*64*8 = 574,464 (+512 pad)
#define WS_TOTAL (WS_FRAGG + 574464 + 512)   // 1,143,296

// LDS layout (bytes)
#define L_REST 0                             // 8*33*64*8 = 135,168
#define L_VST  135168                        // 16*552*2  = 17,664
#define L_PSUM (L_VST + 17664)               // 4*16*4    = 256
#define L_SIG  (L_PSUM + 256)                // lsig/linv/llac 3*16*4 = 192
#define LDS_TOTAL (L_SIG + 192)              // 153,280

__device__ __forceinline__ unsigned bfbits(float x) {
    unsigned u = __builtin_bit_cast(unsigned, x);
    unsigned r = u + 0x7FFFu + ((u >> 16) & 1u);
    return r >> 16;
}

__global__ void prep_A(const float* __restrict__ logA, unsigned* __restrict__ AMATh) {
    __shared__ float red[4];
    __shared__ float srow[Qn];
    int row = blockIdx.x, tid = threadIdx.x;
    if (row >= Qn) {           // pad rows 515..543 -> zero
        for (int c = tid; c < 260; c += 256) AMATh[(size_t)row*260 + c] = 0u;
        return;
    }
    float mx = -1e30f;
    for (int c = tid; c < Qn; c += 256) { float x = logA[(size_t)row*Qn + c]; srow[c] = x; mx = fmaxf(mx, x); }
#pragma unroll
    for (int o = 32; o > 0; o >>= 1) mx = fmaxf(mx, __shfl_xor(mx, o));
    if ((tid & 63) == 0) red[tid >> 6] = mx;
    __syncthreads();
    mx = fmaxf(fmaxf(red[0], red[1]), fmaxf(red[2], red[3]));
    __syncthreads();
    float sm = 0.f;
    for (int c = tid; c < Qn; c += 256) sm += __expf(srow[c] - mx);
#pragma unroll
    for (int o = 32; o > 0; o >>= 1) sm += __shfl_xor(sm, o);
    if ((tid & 63) == 0) red[tid >> 6] = sm;
    __syncthreads();
    float inv = 1.f / (red[0] + red[1] + red[2] + red[3]);
    for (int c2 = tid; c2 < 260; c2 += 256) {
        int c = 2*c2;
        float v0 = (c   < Qn) ? __expf(srow[c]   - mx) * inv : 0.f;
        float v1 = (c+1 < Qn) ? __expf(srow[c+1] - mx) * inv : 0.f;
        AMATh[(size_t)row*260 + c2] = bfbits(v0) | (bfbits(v1) << 16);
    }
}

__global__ void prep_init(const float* __restrict__ il, float* __restrict__ INITD) {
    __shared__ float red[4];
    __shared__ float srow[Qn];
    int tid = threadIdx.x;
    float mx = -1e30f;
    for (int c = tid; c < Qn; c += 256) { float x = il[c]; srow[c] = x; mx = fmaxf(mx, x); }
#pragma unroll
    for (int o = 32; o > 0; o >>= 1) mx = fmaxf(mx, __shfl_xor(mx, o));
    if ((tid & 63) == 0) red[tid >> 6] = mx;
    __syncthreads();
    mx = fmaxf(fmaxf(red[0], red[1]), fmaxf(red[2], red[3]));
    __syncthreads();
    float sm = 0.f;
    for (int c = tid; c < Qn; c += 256) sm += __expf(srow[c] - mx);
#pragma unroll
    for (int o = 32; o > 0; o >>= 1) sm += __shfl_xor(sm, o);
    if ((tid & 63) == 0) red[tid >> 6] = sm;
    __syncthreads();
    float inv = 1.f / (red[0] + red[1] + red[2] + red[3]);
    for (int c = tid; c < 520; c += 256)
        INITD[c] = (c < Qn) ? __expf(srow[c] - mx) * inv : 0.f;
}

// pack A into MFMA B-fragment order: FRAGG[(kt*33+nt)*64 + lane]
__global__ void prep_frag(const unsigned* __restrict__ AMATh, uint2* __restrict__ FRAGG) {
    int t = blockIdx.x*4 + (threadIdx.x >> 6);
    if (t >= KTT*NTT) return;
    int lane = threadIdx.x & 63;
    int kt = t / NTT, nt = t - kt*NTT;
    int col = nt*16 + (lane & 15);
    int kb  = kt*16 + ((lane >> 4) << 2);
    unsigned hh[4];
#pragma unroll
    for (int i = 0; i < 4; ++i) {
        int k = kb + i;                     // < 544; rows >= 515 are zero in AMATh
        unsigned hv = 0;
        if (col < 520) {
            unsigned w = AMATh[(size_t)k*260 + (col >> 1)];
            hv = (col & 1) ? (w >> 16) : (w & 0xffffu);
        }
        hh[i] = hv;
    }
    uint2 pk; pk.x = hh[0] | (hh[1] << 16); pk.y = hh[2] | (hh[3] << 16);
    FRAGG[(size_t)t*64 + lane] = pk;
}

__global__ void __launch_bounds__(256, 1)
hmm_fwd(const float* __restrict__ E, const uint2* __restrict__ FRAGG,
        const float* __restrict__ INITD, float* __restrict__ out)
{
    extern __shared__ char smem[];
    uint2* rest = (uint2*)(smem + L_REST);                      // [8*33*64]
    unsigned short* vstage = (unsigned short*)(smem + L_VST);   // [16][VSTR] (always NORMALIZED)
    u32t* vstage32 = (u32t*)vstage;
    float* psum = (float*)(smem + L_PSUM);                      // [4][16]
    float* lsig = (float*)(smem + L_SIG);                       // [16]
    float* linv = lsig + 16;                                    // [16]
    float* llac = lsig + 32;                                    // [16]

    const int tid  = threadIdx.x;
    const int lane = tid & 63;
    const int wv   = tid >> 6;
    const int b0   = blockIdx.x * ROWS;
    const int nb   = (wv == 0) ? 0 : (wv*8 + 1);    // wave nt ranges: 9,8,8,8
    const int nc   = (wv == 0) ? 9 : 8;
    const int h    = lane >> 4;
    const int cl   = lane & 15;

    // ---- startup: resident frags -> LDS; zero vstage; zero ll ----
    for (int p = tid; p < KR*NTT*64; p += 256) rest[p] = FRAGG[p];
    for (int p = tid; p < 16*(VSTR/2); p += 256) vstage32[p] = 0u;
    if (tid < 16) llac[tid] = 0.f;
    __syncthreads();

    // ---- per-lane maps ----
    int  ecol[9]; bool cok[9];
#pragma unroll
    for (int n = 0; n < 9; ++n) {
        int q = (nb + n)*16 + cl;
        cok[n]  = (n < nc) && (q < Qn);
        ecol[n] = q;
    }

    // tail: sigma-reduce -> stats -> normalized vstage write + log outputs (all from regs).
    // B1 doubles as the barrier separating this step's MFMA vstage-READS from the
    // vstage-WRITES below (the r11 race). vstage only ever holds normalized values.
    auto tail = [&](float (&u)[9][4], float s4[4], int s) {
#pragma unroll
        for (int r = 0; r < 4; ++r) {
#pragma unroll
            for (int m = 1; m < 16; m <<= 1) s4[r] += __shfl_xor(s4[r], m);
            if (cl == 0) psum[wv*16 + 4*h + r] = s4[r];
        }
        __syncthreads();                       // B1
        if (tid < 16) {
            float sg = psum[tid] + psum[16 + tid] + psum[32 + tid] + psum[48 + tid];
            float ls = __logf(sg);
            lsig[tid] = ls; linv[tid] = 1.f / sg;
            float ll = llac[tid] + ls; llac[tid] = ll;
            out[((size_t)(b0 + tid)*Tn + s)*OQ + Qn] = ll;
        }
        __syncthreads();                       // B2
#pragma unroll
        for (int r = 0; r < 4; ++r) {
            int row = 4*h + r;
            float ls = lsig[row], iv = linv[row];
            float* orow = out + ((size_t)(b0 + row)*Tn + s)*OQ;
#pragma unroll
            for (int n = 0; n < 9; ++n) {
                float uv = u[n][r];
                float nv = uv * iv;
                float nn = __shfl_xor(nv, 1);
                if (!(lane & 1) && n < nc)
                    vstage32[row*(VSTR/2) + (((nb + n)*16 + cl) >> 1)]
                        = bfbits(nv) | (bfbits(nn) << 16);
                if (cok[n]) orow[ecol[n]] = __logf(uv) - ls;
            }
        }
        __syncthreads();                       // B3: vstage ready for next step's MFMA
    };

    // ---- t = 0 : u0 = max(E0,eps)*max(init,eps) ----
    {
        float u[9][4]; float s4[4] = {0.f, 0.f, 0.f, 0.f};
#pragma unroll
        for (int n = 0; n < 9; ++n) {
            float idv = cok[n] ? fmaxf(INITD[ecol[n]], EPSc) : 0.f;
#pragma unroll
            for (int r = 0; r < 4; ++r) {
                float e  = cok[n] ? E[(size_t)(b0 + 4*h + r)*Qn + ecol[n]] : 0.f;
                float uv = cok[n] ? fmaxf(e, EPSc) * idv : 0.f;
                u[n][r] = uv; s4[r] += uv;
            }
        }
        tail(u, s4, 0);
    }

    // ---- main loop: full matvec per block (LDS-resident + L2-streamed fragments) ----
    const unsigned short* arow = vstage + cl*VSTR + (h << 2);
    for (int s = 1; s < Tn; ++s) {
        // E prefetch (consumed in epilogue; HBM latency hides under the MFMA loop)
        float evv[9][4];
        size_t ebase = (size_t)s * (Bn*Qn);
#pragma unroll
        for (int n = 0; n < 9; ++n)
#pragma unroll
            for (int r = 0; r < 4; ++r)
                evv[n][r] = cok[n] ? E[ebase + (size_t)(b0 + 4*h + r)*Qn + ecol[n]] : 0.f;

        // stream prologue: k-tiles KR..KR+ND-1 into rolling register window
        uint2 bw[ND][9];
#pragma unroll
        for (int d = 0; d < ND; ++d)
#pragma unroll
            for (int n = 0; n < 9; ++n)
                if (n < nc) bw[d][n] = FRAGG[(size_t)(((KR + d)*NTT + nb + n)*64 + lane)];

        f32x4 acc[9];
#pragma unroll
        for (int n = 0; n < 9; ++n) acc[n] = f32x4{0.f, 0.f, 0.f, 0.f};

        // resident k-tiles
#pragma unroll
        for (int kt = 0; kt < KR; ++kt) {
            s16x4 a = __builtin_bit_cast(s16x4, *(const uint2*)(arow + kt*16));
#pragma unroll
            for (int n = 0; n < 9; ++n)
                if (n < nc)
                    acc[n] = __builtin_amdgcn_mfma_f32_16x16x16bf16_1k(
                        a, __builtin_bit_cast(s16x4, rest[(kt*NTT + nb + n)*64 + lane]),
                        acc[n], 0, 0, 0);
        }
        // streamed k-tiles: kt = KR + c*ND + d  (all indices literal after unroll)
#pragma unroll
        for (int c = 0; c < NSTP; ++c) {
#pragma unroll
            for (int d = 0; d < ND; ++d) {
                const int kt = KR + c*ND + d;
                if (kt < KTT) {
                    s16x4 a = __builtin_bit_cast(s16x4, *(const uint2*)(arow + kt*16));
#pragma unroll
                    for (int n = 0; n < 9; ++n)
                        if (n < nc)
                            acc[n] = __builtin_amdgcn_mfma_f32_16x16x16bf16_1k(
                                a, __builtin_bit_cast(s16x4, bw[d][n]), acc[n], 0, 0, 0);
                    if (kt + ND < KTT) {
#pragma unroll
                        for (int n = 0; n < 9; ++n)
                            if (n < nc)
                                bw[d][n] = FRAGG[(size_t)(((kt + ND)*NTT + nb + n)*64 + lane)];
                    }
                }
            }
        }

        // epilogue: u = max(E,eps) * max(R,eps) -> registers only (no LDS writes here)
        float u[9][4]; float s4[4] = {0.f, 0.f, 0.f, 0.f};
#pragma unroll
        for (int n = 0; n < 9; ++n)
#pragma unroll
            for (int r = 0; r < 4; ++r) {
                float R  = fmaxf(acc[n][r], EPSc);
                float uv = cok[n] ? fmaxf(evv[n][r], EPSc) * R : 0.f;
                u[n][r] = uv; s4[r] += uv;
            }
        tail(u, s4, s);
    }
}

extern "C" void kernel_launch(void* const* d_in, const int* in_sizes, int n_in,
                              void* d_out, int out_size, void* d_ws, size_t ws_size,
                              hipStream_t stream) {
    (void)in_sizes; (void)n_in; (void)out_size;
    if (ws_size < (size_t)WS_TOTAL) return;

    const float* E    = (const float*)d_in[0];
    const float* logA = (const float*)d_in[1];
    const float* il   = (const float*)d_in[2];
    float* out = (float*)d_out;
    char*  ws  = (char*)d_ws;

    unsigned* AMATh = (unsigned*)(ws + WS_AMATH);
    float*    INITD = (float*)(ws + WS_INIT);
    uint2*    FRAGG = (uint2*)(ws + WS_FRAGG);

    prep_A<<<544, 256, 0, stream>>>(logA, AMATh);
    prep_init<<<1, 256, 0, stream>>>(il, INITD);
    prep_frag<<<(KTT*NTT + 3)/4, 256, 0, stream>>>(AMATh, FRAGG);

    static_assert(LDS_TOTAL < 160*1024, "LDS budget");
    hipFuncSetAttribute(reinterpret_cast<const void*>(hmm_fwd),
                        hipFuncAttributeMaxDynamicSharedMemorySize, LDS_TOTAL);
    hmm_fwd<<<NBLK, 256, LDS_TOTAL, stream>>>(E, FRAGG, INITD, out);
}